// Round 1
// baseline (1830.532 us; speedup 1.0000x reference)
//
#include <hip/hip_runtime.h>
#include <math.h>

static constexpr int NN  = 1000000;   // nodes
static constexpr int HD  = 128;       // memory dim
static constexpr int ED  = 64;        // edge dim
static constexpr int TD  = 16;        // time dim
static constexpr int NE  = 100000;    // events
static constexpr int GIN = 336;       // 2*HD + ED + TD
static constexpr int EB  = 16;        // events per block

// ---------------- priority pass: last-write-wins resolution ----------------
// src write of event e has key e; dst write has key NE+e (dst applied after
// all src, later events beat earlier). Winner per node = max key.
__global__ void prio_kernel(const int* __restrict__ src, const int* __restrict__ dst,
                            int* __restrict__ prio) {
    int e = blockIdx.x * blockDim.x + threadIdx.x;
    if (e < NE) {
        atomicMax(&prio[src[e]], e);
        atomicMax(&prio[dst[e]], NE + e);
    }
}

// ---------------- full memory copy into output ----------------
__global__ void copy_kernel(const float4* __restrict__ in, float4* __restrict__ out) {
    const int total = NN * (HD / 4);
    int stride = gridDim.x * blockDim.x;
    for (int i = blockIdx.x * blockDim.x + threadIdx.x; i < total; i += stride)
        out[i] = in[i];
}

// ---------------- fused gather + time-enc + GRU + winner scatter ----------------
// 128 threads: thread i owns hidden unit i (needs W rows i, i+128, i+256).
// EB events staged in LDS as inp[e] = [s | d | ef | te] (336 floats).
__global__ __launch_bounds__(128) void gru_kernel(
    const float* __restrict__ memory,
    const int* __restrict__ src, const int* __restrict__ dst,
    const float* __restrict__ ts, const float* __restrict__ ef,
    const float* __restrict__ W_time, const float* __restrict__ b_time,
    const float* __restrict__ W_ih, const float* __restrict__ W_hh,
    const float* __restrict__ b_ih, const float* __restrict__ b_hh,
    const int* __restrict__ prio, float* __restrict__ mem_out)
{
    __shared__ float inp[EB][GIN];
    const int tid = threadIdx.x;
    const int e0 = blockIdx.x * EB;

    // stage s, d, ef (80 float4 per event)
    for (int idx = tid; idx < EB * 80; idx += 128) {
        int e = idx / 80, p = idx % 80;
        float4 v; int doff;
        if (p < 32) {
            v = ((const float4*)&memory[(size_t)src[e0 + e] * HD])[p];
            doff = p * 4;
        } else if (p < 64) {
            v = ((const float4*)&memory[(size_t)dst[e0 + e] * HD])[p - 32];
            doff = 128 + (p - 32) * 4;
        } else {
            v = ((const float4*)&ef[(size_t)(e0 + e) * ED])[p - 64];
            doff = 256 + (p - 64) * 4;
        }
        *(float4*)&inp[e][doff] = v;
    }
    // time encoding
    for (int idx = tid; idx < EB * TD; idx += 128) {
        int e = idx / TD, j = idx % TD;
        inp[e][2 * HD + ED + j] = sinf(ts[e0 + e] * W_time[j] + b_time[j]);
    }
    __syncthreads();

    const int i = tid;  // hidden unit

    // gi = inp @ W_ih^T  (shared by both GRU evaluations)
    float gr[EB], gz[EB], gn[EB];
#pragma unroll
    for (int e = 0; e < EB; ++e) { gr[e] = 0.f; gz[e] = 0.f; gn[e] = 0.f; }
    {
        const float4* Wr = (const float4*)&W_ih[(size_t)i * GIN];
        const float4* Wz = (const float4*)&W_ih[(size_t)(i + 128) * GIN];
        const float4* Wn = (const float4*)&W_ih[(size_t)(i + 256) * GIN];
        for (int k = 0; k < GIN / 4; ++k) {
            float4 wr = Wr[k], wz = Wz[k], wn = Wn[k];
#pragma unroll
            for (int e = 0; e < EB; ++e) {
                float4 x = *(const float4*)&inp[e][k * 4];
                gr[e] += wr.x * x.x + wr.y * x.y + wr.z * x.z + wr.w * x.w;
                gz[e] += wz.x * x.x + wz.y * x.y + wz.z * x.z + wz.w * x.w;
                gn[e] += wn.x * x.x + wn.y * x.y + wn.z * x.z + wn.w * x.w;
            }
        }
    }
    const float bir = b_ih[i], biz = b_ih[i + 128], bin_ = b_ih[i + 256];
    const float bhr = b_hh[i], bhz = b_hh[i + 128], bhn = b_hh[i + 256];
#pragma unroll
    for (int e = 0; e < EB; ++e) { gr[e] += bir; gz[e] += biz; gn[e] += bin_; }

    const float4* Vr = (const float4*)&W_hh[(size_t)i * HD];
    const float4* Vz = (const float4*)&W_hh[(size_t)(i + 128) * HD];
    const float4* Vn = (const float4*)&W_hh[(size_t)(i + 256) * HD];

    for (int pass = 0; pass < 2; ++pass) {        // pass 0: h = s, pass 1: h = d
        const int hoff = pass * HD;
        float hr[EB], hz[EB], hn[EB];
#pragma unroll
        for (int e = 0; e < EB; ++e) { hr[e] = 0.f; hz[e] = 0.f; hn[e] = 0.f; }
        for (int k = 0; k < HD / 4; ++k) {
            float4 vr = Vr[k], vz = Vz[k], vn = Vn[k];
#pragma unroll
            for (int e = 0; e < EB; ++e) {
                float4 x = *(const float4*)&inp[e][hoff + k * 4];
                hr[e] += vr.x * x.x + vr.y * x.y + vr.z * x.z + vr.w * x.w;
                hz[e] += vz.x * x.x + vz.y * x.y + vz.z * x.z + vz.w * x.w;
                hn[e] += vn.x * x.x + vn.y * x.y + vn.z * x.z + vn.w * x.w;
            }
        }
#pragma unroll
        for (int e = 0; e < EB; ++e) {
            float r = 1.f / (1.f + expf(-(gr[e] + hr[e] + bhr)));
            float z = 1.f / (1.f + expf(-(gz[e] + hz[e] + bhz)));
            float n = tanhf(gn[e] + r * (hn[e] + bhn));
            float h = inp[e][hoff + i];
            float nv = (1.f - z) * n + z * h;
            int ev = e0 + e;
            int node = (pass == 0) ? src[ev] : dst[ev];
            int key  = (pass == 0) ? ev : NE + ev;
            if (prio[node] == key)
                mem_out[(size_t)node * HD + i] = nv;   // unique winner per row
        }
    }
}

// ---------------- predictor on updated memory ----------------
__global__ __launch_bounds__(128) void pred_kernel(
    const float* __restrict__ mem,
    const int* __restrict__ src, const int* __restrict__ dst,
    const float* __restrict__ W_p1, const float* __restrict__ b_p1,
    const float* __restrict__ W_p2, const float* __restrict__ b_p2,
    float* __restrict__ pred)
{
    __shared__ float h[EB][2 * HD];
    __shared__ float partial[EB][2];
    const int tid = threadIdx.x;
    const int e0 = blockIdx.x * EB;

    for (int idx = tid; idx < EB * 64; idx += 128) {
        int e = idx / 64, p = idx % 64;
        int off = p & 31;
        float4 v = (p < 32)
            ? ((const float4*)&mem[(size_t)src[e0 + e] * HD])[off]
            : ((const float4*)&mem[(size_t)dst[e0 + e] * HD])[off];
        *(float4*)&h[e][(p < 32 ? 0 : HD) + off * 4] = v;
    }
    __syncthreads();

    const int i = tid;
    float acc[EB];
#pragma unroll
    for (int e = 0; e < EB; ++e) acc[e] = b_p1[i];
    const float4* W = (const float4*)&W_p1[(size_t)i * (2 * HD)];
    for (int k = 0; k < (2 * HD) / 4; ++k) {
        float4 w = W[k];
#pragma unroll
        for (int e = 0; e < EB; ++e) {
            float4 x = *(const float4*)&h[e][k * 4];
            acc[e] += w.x * x.x + w.y * x.y + w.z * x.z + w.w * x.w;
        }
    }
    const float w2 = W_p2[i];
#pragma unroll
    for (int e = 0; e < EB; ++e) {
        float ph = acc[e] > 0.f ? acc[e] : 0.f;
        float p = ph * w2;
        for (int off = 32; off; off >>= 1) p += __shfl_down(p, off, 64);
        if ((tid & 63) == 0) partial[e][tid >> 6] = p;
    }
    __syncthreads();
    if (tid < EB) pred[e0 + tid] = partial[tid][0] + partial[tid][1] + b_p2[0];
}

extern "C" void kernel_launch(void* const* d_in, const int* in_sizes, int n_in,
                              void* d_out, int out_size, void* d_ws, size_t ws_size,
                              hipStream_t stream) {
    const float* memory = (const float*)d_in[0];
    const int*   src    = (const int*)d_in[1];
    const int*   dst    = (const int*)d_in[2];
    const float* ts     = (const float*)d_in[3];
    const float* ef     = (const float*)d_in[4];
    const float* W_time = (const float*)d_in[5];
    const float* b_time = (const float*)d_in[6];
    const float* W_ih   = (const float*)d_in[7];
    const float* W_hh   = (const float*)d_in[8];
    const float* b_ih   = (const float*)d_in[9];
    const float* b_hh   = (const float*)d_in[10];
    const float* W_p1   = (const float*)d_in[11];
    const float* b_p1   = (const float*)d_in[12];
    const float* W_p2   = (const float*)d_in[13];
    const float* b_p2   = (const float*)d_in[14];

    float* pred    = (float*)d_out;           // [NE]
    float* mem_out = pred + NE;               // [NN, HD]
    int*   prio    = (int*)d_ws;              // [NN]

    hipMemsetAsync(prio, 0xFF, (size_t)NN * sizeof(int), stream);  // -1
    prio_kernel<<<(NE + 255) / 256, 256, 0, stream>>>(src, dst, prio);
    copy_kernel<<<4096, 256, 0, stream>>>((const float4*)memory, (float4*)mem_out);
    gru_kernel<<<NE / EB, 128, 0, stream>>>(memory, src, dst, ts, ef,
                                            W_time, b_time, W_ih, W_hh, b_ih, b_hh,
                                            prio, mem_out);
    pred_kernel<<<NE / EB, 128, 0, stream>>>(mem_out, src, dst,
                                             W_p1, b_p1, W_p2, b_p2, pred);
}

// Round 2
// 698.021 us; speedup vs baseline: 2.6225x; 2.6225x over previous
//
#include <hip/hip_runtime.h>
#include <hip/hip_bf16.h>
#include <math.h>

static constexpr int NN  = 1000000;   // nodes
static constexpr int HD  = 128;       // memory dim
static constexpr int ED  = 64;        // edge dim
static constexpr int TD  = 16;        // time dim
static constexpr int NE  = 100000;    // events
static constexpr int GIN = 336;       // 2*HD + ED + TD
static constexpr int KP  = 352;       // GIN padded to mult of 32
static constexpr int KS  = KP / 32;   // 11 K-steps
static constexpr int EB  = 16;        // events per block

typedef __attribute__((ext_vector_type(8))) short bf16x8;
typedef __attribute__((ext_vector_type(4))) float f32x4;

__device__ inline unsigned short f2bf(float x) {
    union { float f; unsigned u; } a; a.f = x;
    unsigned r = a.u + 0x7fff + ((a.u >> 16) & 1);   // RNE
    return (unsigned short)(r >> 16);
}

// ---------------- priority pass: last-write-wins resolution ----------------
__global__ void prio_kernel(const int* __restrict__ src, const int* __restrict__ dst,
                            int* __restrict__ prio) {
    int e = blockIdx.x * blockDim.x + threadIdx.x;
    if (e < NE) {
        atomicMax(&prio[src[e]], e);
        atomicMax(&prio[dst[e]], NE + e);
    }
}

// ---------------- full memory copy into output ----------------
__global__ void copy_kernel(const float4* __restrict__ in, float4* __restrict__ out) {
    const int total = NN * (HD / 4);
    int stride = gridDim.x * blockDim.x;
    for (int i = blockIdx.x * blockDim.x + threadIdx.x; i < total; i += stride)
        out[i] = in[i];
}

// ------------- weight repack: f32 -> bf16, MFMA-fragment-linear -------------
// Wihf[t][kk][lane][8]: t = gate*8 + w (rows t*16+(lane&15)), k = kk*32+(lane>>4)*8+j
__global__ void wconv_kernel(const float* __restrict__ W_ih, const float* __restrict__ W_hh,
                             unsigned short* __restrict__ Wihf, unsigned short* __restrict__ Whhf) {
    const int NIH = 24 * KS * 512;
    const int NHH = 24 * 4 * 512;
    int q = blockIdx.x * blockDim.x + threadIdx.x;
    if (q < NIH) {
        int t   = q / (KS * 512);
        int rem = q % (KS * 512);
        int kk  = rem / 512;
        int li  = rem % 512;
        int l = li >> 3, j = li & 7;
        int row = t * 16 + (l & 15);
        int col = kk * 32 + (l >> 4) * 8 + j;
        Wihf[q] = (col < GIN) ? f2bf(W_ih[(size_t)row * GIN + col]) : (unsigned short)0;
    } else if (q < NIH + NHH) {
        int p   = q - NIH;
        int t   = p / (4 * 512);
        int rem = p % (4 * 512);
        int kk  = rem / 512;
        int li  = rem % 512;
        int l = li >> 3, j = li & 7;
        int row = t * 16 + (l & 15);
        int col = kk * 32 + (l >> 4) * 8 + j;
        Whhf[p] = f2bf(W_hh[(size_t)row * HD + col]);
    }
}

// -------- fused gather + time-enc + MFMA GRU + winner scatter --------
// 8 waves; wave w owns units 16w..16w+15; 16 events/block staged bf16 in LDS.
__global__ __launch_bounds__(512) void gru_kernel(
    const float* __restrict__ memory,
    const int* __restrict__ src, const int* __restrict__ dst,
    const float* __restrict__ ts, const float* __restrict__ ef,
    const float* __restrict__ W_time, const float* __restrict__ b_time,
    const unsigned short* __restrict__ Wihf, const unsigned short* __restrict__ Whhf,
    const float* __restrict__ b_ih, const float* __restrict__ b_hh,
    const int* __restrict__ prio, float* __restrict__ mem_out)
{
    __shared__ unsigned short a_lds[EB * KP];       // 11264 B
    const int tid = threadIdx.x;
    const int e0  = blockIdx.x * EB;

    // ---- stage inp = [s | d | ef | te | 0pad] as bf16 pairs ----
    unsigned* a32 = (unsigned*)a_lds;
    for (int idx = tid; idx < EB * (KP / 2); idx += 512) {
        int e = idx / (KP / 2), c = idx % (KP / 2);
        float x0 = 0.f, x1 = 0.f;
        if (c < 64) {
            const float* p = &memory[(size_t)src[e0 + e] * HD + 2 * c];
            x0 = p[0]; x1 = p[1];
        } else if (c < 128) {
            const float* p = &memory[(size_t)dst[e0 + e] * HD + 2 * (c - 64)];
            x0 = p[0]; x1 = p[1];
        } else if (c < 160) {
            const float* p = &ef[(size_t)(e0 + e) * ED + 2 * (c - 128)];
            x0 = p[0]; x1 = p[1];
        } else if (c < 168) {
            int j = 2 * (c - 160);
            float t = ts[e0 + e];
            x0 = sinf(t * W_time[j]     + b_time[j]);
            x1 = sinf(t * W_time[j + 1] + b_time[j + 1]);
        }
        a32[idx] = (unsigned)f2bf(x0) | ((unsigned)f2bf(x1) << 16);
    }
    __syncthreads();

    const int w    = tid >> 6;
    const int lane = tid & 63;
    const int lg   = lane >> 4;
    const int u    = w * 16 + (lane & 15);          // output unit

    f32x4 ir = {0.f,0.f,0.f,0.f}, iz = ir, in_ = ir;
    f32x4 sr = ir, sz = ir, sn = ir;
    f32x4 dr = ir, dz = ir, dn = ir;

#pragma unroll
    for (int kk = 0; kk < KS; ++kk) {
        bf16x8 a = *(const bf16x8*)&a_lds[(lane & 15) * KP + kk * 32 + lg * 8];
        {   // gi: W_ih rows {u, u+128, u+256}
            bf16x8 b0 = *(const bf16x8*)&Wihf[(((size_t)(0 * 8 + w) * KS + kk) * 64 + lane) * 8];
            bf16x8 b1 = *(const bf16x8*)&Wihf[(((size_t)(1 * 8 + w) * KS + kk) * 64 + lane) * 8];
            bf16x8 b2 = *(const bf16x8*)&Wihf[(((size_t)(2 * 8 + w) * KS + kk) * 64 + lane) * 8];
            ir  = __builtin_amdgcn_mfma_f32_16x16x32_bf16(a, b0, ir , 0, 0, 0);
            iz  = __builtin_amdgcn_mfma_f32_16x16x32_bf16(a, b1, iz , 0, 0, 0);
            in_ = __builtin_amdgcn_mfma_f32_16x16x32_bf16(a, b2, in_, 0, 0, 0);
        }
        if (kk < 4) {      // gh_s: A-cols = s
            bf16x8 b0 = *(const bf16x8*)&Whhf[(((size_t)(0 * 8 + w) * 4 + kk) * 64 + lane) * 8];
            bf16x8 b1 = *(const bf16x8*)&Whhf[(((size_t)(1 * 8 + w) * 4 + kk) * 64 + lane) * 8];
            bf16x8 b2 = *(const bf16x8*)&Whhf[(((size_t)(2 * 8 + w) * 4 + kk) * 64 + lane) * 8];
            sr = __builtin_amdgcn_mfma_f32_16x16x32_bf16(a, b0, sr, 0, 0, 0);
            sz = __builtin_amdgcn_mfma_f32_16x16x32_bf16(a, b1, sz, 0, 0, 0);
            sn = __builtin_amdgcn_mfma_f32_16x16x32_bf16(a, b2, sn, 0, 0, 0);
        } else if (kk < 8) {  // gh_d: A-cols = d, same W_hh
            int k2 = kk - 4;
            bf16x8 b0 = *(const bf16x8*)&Whhf[(((size_t)(0 * 8 + w) * 4 + k2) * 64 + lane) * 8];
            bf16x8 b1 = *(const bf16x8*)&Whhf[(((size_t)(1 * 8 + w) * 4 + k2) * 64 + lane) * 8];
            bf16x8 b2 = *(const bf16x8*)&Whhf[(((size_t)(2 * 8 + w) * 4 + k2) * 64 + lane) * 8];
            dr = __builtin_amdgcn_mfma_f32_16x16x32_bf16(a, b0, dr, 0, 0, 0);
            dz = __builtin_amdgcn_mfma_f32_16x16x32_bf16(a, b1, dz, 0, 0, 0);
            dn = __builtin_amdgcn_mfma_f32_16x16x32_bf16(a, b2, dn, 0, 0, 0);
        }
    }

    // ---- GRU nonlinearity + winner scatter ----
    const float bir = b_ih[u], biz = b_ih[u + 128], bin_ = b_ih[u + 256];
    const float bhr = b_hh[u], bhz = b_hh[u + 128], bhn = b_hh[u + 256];
#pragma unroll
    for (int j = 0; j < 4; ++j) {
        int e = e0 + lg * 4 + j;                    // C/D: row=(lane>>4)*4+reg
        float gr_ = ir[j] + bir, gz_ = iz[j] + biz, gn_ = in_[j] + bin_;
        {   // src update
            int node = src[e];
            float r = 1.f / (1.f + expf(-(gr_ + sr[j] + bhr)));
            float z = 1.f / (1.f + expf(-(gz_ + sz[j] + bhz)));
            float n = tanhf(gn_ + r * (sn[j] + bhn));
            float h = memory[(size_t)node * HD + u];
            float nv = (1.f - z) * n + z * h;
            if (prio[node] == e) mem_out[(size_t)node * HD + u] = nv;
        }
        {   // dst update
            int node = dst[e];
            float r = 1.f / (1.f + expf(-(gr_ + dr[j] + bhr)));
            float z = 1.f / (1.f + expf(-(gz_ + dz[j] + bhz)));
            float n = tanhf(gn_ + r * (dn[j] + bhn));
            float h = memory[(size_t)node * HD + u];
            float nv = (1.f - z) * n + z * h;
            if (prio[node] == NE + e) mem_out[(size_t)node * HD + u] = nv;
        }
    }
}

// ---------------- predictor on updated memory ----------------
__global__ __launch_bounds__(128) void pred_kernel(
    const float* __restrict__ mem,
    const int* __restrict__ src, const int* __restrict__ dst,
    const float* __restrict__ W_p1, const float* __restrict__ b_p1,
    const float* __restrict__ W_p2, const float* __restrict__ b_p2,
    float* __restrict__ pred)
{
    __shared__ float h[EB][2 * HD];
    __shared__ float partial[EB][2];
    const int tid = threadIdx.x;
    const int e0 = blockIdx.x * EB;

    for (int idx = tid; idx < EB * 64; idx += 128) {
        int e = idx / 64, p = idx % 64;
        int off = p & 31;
        float4 v = (p < 32)
            ? ((const float4*)&mem[(size_t)src[e0 + e] * HD])[off]
            : ((const float4*)&mem[(size_t)dst[e0 + e] * HD])[off];
        *(float4*)&h[e][(p < 32 ? 0 : HD) + off * 4] = v;
    }
    __syncthreads();

    const int i = tid;
    float acc[EB];
#pragma unroll
    for (int e = 0; e < EB; ++e) acc[e] = b_p1[i];
    const float4* W = (const float4*)&W_p1[(size_t)i * (2 * HD)];
    for (int k = 0; k < (2 * HD) / 4; ++k) {
        float4 w = W[k];
#pragma unroll
        for (int e = 0; e < EB; ++e) {
            float4 x = *(const float4*)&h[e][k * 4];
            acc[e] += w.x * x.x + w.y * x.y + w.z * x.z + w.w * x.w;
        }
    }
    const float w2 = W_p2[i];
#pragma unroll
    for (int e = 0; e < EB; ++e) {
        float ph = acc[e] > 0.f ? acc[e] : 0.f;
        float p = ph * w2;
        for (int off = 32; off; off >>= 1) p += __shfl_down(p, off, 64);
        if ((tid & 63) == 0) partial[e][tid >> 6] = p;
    }
    __syncthreads();
    if (tid < EB) pred[e0 + tid] = partial[tid][0] + partial[tid][1] + b_p2[0];
}

extern "C" void kernel_launch(void* const* d_in, const int* in_sizes, int n_in,
                              void* d_out, int out_size, void* d_ws, size_t ws_size,
                              hipStream_t stream) {
    const float* memory = (const float*)d_in[0];
    const int*   src    = (const int*)d_in[1];
    const int*   dst    = (const int*)d_in[2];
    const float* ts     = (const float*)d_in[3];
    const float* ef     = (const float*)d_in[4];
    const float* W_time = (const float*)d_in[5];
    const float* b_time = (const float*)d_in[6];
    const float* W_ih   = (const float*)d_in[7];
    const float* W_hh   = (const float*)d_in[8];
    const float* b_ih   = (const float*)d_in[9];
    const float* b_hh   = (const float*)d_in[10];
    const float* W_p1   = (const float*)d_in[11];
    const float* b_p1   = (const float*)d_in[12];
    const float* W_p2   = (const float*)d_in[13];
    const float* b_p2   = (const float*)d_in[14];

    float* pred    = (float*)d_out;                 // [NE]
    float* mem_out = pred + NE;                     // [NN, HD]

    int* prio = (int*)d_ws;                                         // 4 MB
    unsigned short* Wihf = (unsigned short*)((char*)d_ws + (size_t)NN * 4);
    unsigned short* Whhf = Wihf + 24 * KS * 512;                    // +270336 B

    hipMemsetAsync(prio, 0xFF, (size_t)NN * sizeof(int), stream);   // -1
    wconv_kernel<<<(24 * KS * 512 + 24 * 4 * 512 + 255) / 256, 256, 0, stream>>>(
        W_ih, W_hh, Wihf, Whhf);
    prio_kernel<<<(NE + 255) / 256, 256, 0, stream>>>(src, dst, prio);
    copy_kernel<<<8192, 256, 0, stream>>>((const float4*)memory, (float4*)mem_out);
    gru_kernel<<<NE / EB, 512, 0, stream>>>(memory, src, dst, ts, ef,
                                            W_time, b_time, Wihf, Whhf, b_ih, b_hh,
                                            prio, mem_out);
    pred_kernel<<<NE / EB, 128, 0, stream>>>(mem_out, src, dst,
                                             W_p1, b_p1, W_p2, b_p2, pred);
}